// Round 5
// baseline (1909.641 us; speedup 1.0000x reference)
//
#include <hip/hip_runtime.h>
#include <math.h>

#define B_ 4
#define T_ 1024
#define D_ 1024
#define H_ 16
#define DFF_ 4096
#define HD_ 64
#define BT_ (B_*T_)
#define PL ((size_t)BT_*D_)   /* elements per fp32 component plane (4M) */

typedef unsigned int uint;
typedef unsigned short ushort;
typedef __attribute__((ext_vector_type(8))) __bf16 bf16x8;
typedef __attribute__((ext_vector_type(4))) float f32x4;
typedef __attribute__((ext_vector_type(4))) uint uint4v;

__device__ __forceinline__ float b2f(ushort u){
  union{uint i; float f;} x; x.i = ((uint)u)<<16; return x.f;
}
__device__ __forceinline__ ushort f2b(float f){
  union{float f; uint i;} x; x.f = f;
  uint r = x.i + 0x7fffu + ((x.i>>16)&1u);
  return (ushort)(r>>16);
}
__device__ __forceinline__ void fsplit(float x, ushort& hi, ushort& lo){
  hi = f2b(x);
  lo = f2b(x - b2f(hi));   // x - hi exact in fp32
}
__device__ __forceinline__ bf16x8 negv(bf16x8 v){
  union{bf16x8 b; uint4v u;} t; t.b = v;
  t.u ^= 0x80008000u;
  return t.b;
}
__device__ __forceinline__ f32x4 mfma16(bf16x8 a, bf16x8 b, f32x4 c){
  return __builtin_amdgcn_mfma_f32_16x16x32_bf16(a,b,c,0,0,0);
}
__device__ __forceinline__ float block_sum(float v, float* sm){
  #pragma unroll
  for (int o=32;o>0;o>>=1) v += __shfl_down(v,o);
  int wid = threadIdx.x>>6;
  if ((threadIdx.x&63)==0) sm[wid]=v;
  __syncthreads();
  float r = sm[0]+sm[1]+sm[2]+sm[3];
  __syncthreads();
  return r;
}

// fp32 complex weight [2][NK] -> split-bf16 [4][NK] (rh, rl, ih, il)
__global__ __launch_bounds__(256) void cvt_split(const float* __restrict__ s,
                                                 ushort* __restrict__ d, long NK){
  long i = ((long)blockIdx.x*256 + threadIdx.x)*4;
  if (i >= NK) return;
  float4 vr = *(const float4*)(s+i);
  float4 vi = *(const float4*)(s+NK+i);
  ushort4 rh, rl, ih4, il4;
  fsplit(vr.x, rh.x, rl.x); fsplit(vr.y, rh.y, rl.y);
  fsplit(vr.z, rh.z, rl.z); fsplit(vr.w, rh.w, rl.w);
  fsplit(vi.x, ih4.x, il4.x); fsplit(vi.y, ih4.y, il4.y);
  fsplit(vi.z, ih4.z, il4.z); fsplit(vi.w, ih4.w, il4.w);
  *(ushort4*)(d + i)        = rh;
  *(ushort4*)(d + NK + i)   = rl;
  *(ushort4*)(d + 2*NK + i) = ih4;
  *(ushort4*)(d + 3*NK + i) = il4;
}

// Per-component LayerNorm over D; fp32 in, split-bf16 out (4 planes).
__global__ __launch_bounds__(256) void cln_kernel(const float* __restrict__ x,
    long PSx, int row0, const float* __restrict__ g, const float* __restrict__ bb,
    ushort* __restrict__ out, long PSo)
{
  __shared__ float sm[4];
  int row = blockIdx.x, comp = blockIdx.y;
  const float* xr = x + (size_t)comp*PSx + (size_t)(row0+row)*D_;
  float4 v = *(const float4*)(xr + threadIdx.x*4);
  float s = v.x+v.y+v.z+v.w;
  s = block_sum(s, sm);
  float mean = s * (1.0f/D_);
  float dx=v.x-mean, dy=v.y-mean, dz=v.z-mean, dw=v.w-mean;
  float s2 = dx*dx+dy*dy+dz*dz+dw*dw;
  s2 = block_sum(s2, sm);
  float inv = 1.0f/sqrtf(s2*(1.0f/D_) + 1e-5f);
  float4 gv = *(const float4*)(g + comp*D_ + threadIdx.x*4);
  float4 bv = *(const float4*)(bb + comp*D_ + threadIdx.x*4);
  float y0 = dx*inv*gv.x + bv.x, y1 = dy*inv*gv.y + bv.y;
  float y2 = dz*inv*gv.z + bv.z, y3 = dw*inv*gv.w + bv.w;
  ushort4 hh, ll;
  fsplit(y0, hh.x, ll.x); fsplit(y1, hh.y, ll.y);
  fsplit(y2, hh.z, ll.z); fsplit(y3, hh.w, ll.w);
  ushort* oh = out + (size_t)(comp*2)*PSo   + (size_t)row*D_;
  ushort* ol = out + (size_t)(comp*2+1)*PSo + (size_t)row*D_;
  *(ushort4*)(oh + threadIdx.x*4) = hh;
  *(ushort4*)(ol + threadIdx.x*4) = ll;
}

// Split-bf16 complex MFMA GEMM: C = A @ W^T + bias (+res) (opt CReLU).
// Double-buffered LDS with depth-2 counted-vmcnt pipeline: raw s_barrier,
// s_waitcnt vmcnt(NPW) waits only for the stage issued 2 steps ago (kept in
// flight across a full compute phase). No vmcnt(0) drain in the main loop.
// XCD-chunked tile remap. LDS layout per buffer: per matrix 2 plane-pairs;
// row of 8 16B slots, physical slot = logical ^ (row&7).
template<int BM,int BN,int WM,int WN>
__global__ __launch_bounds__(256,1) void cgemm_split(
    const ushort* __restrict__ A, long PSa,
    const ushort* __restrict__ W, long PSw, long wstride,
    const float* b0, const float* b1, const float* b2,
    const float* __restrict__ Rr, const float* __restrict__ Ri,
    float* __restrict__ Cf, long PSc, long ostrideF,
    ushort* __restrict__ Cs, long PSs, long ostrideS,
    int M, int N, int K, int relu, int biasRow, int kslice)
{
  constexpr int NI = WM/16, NJ = WN/16;
  constexpr int NWX = BN/WN;
  constexpr int NPW = (BM+BN)/16;     // global_load_lds per wave per K-step
  constexpr int BUF = (BM+BN)*128;    // ushorts per buffer
  __shared__ __align__(16) ushort lds[2*BUF];
  const int tid = threadIdx.x, wave = tid>>6, lane = tid&63;
  const int quad = lane>>4, l16 = lane&15;
  const int lrow = lane>>3, sl = lane&7;

  // XCD-chunked bijective tile remap (nt % 8 == 0 at all call sites)
  const int gx = gridDim.x, gy = gridDim.y;
  const int nt = gx*gy;
  int lin = blockIdx.x + gx*blockIdx.y;
  int tile = (nt&7) ? lin : ((lin&7)*(nt>>3) + (lin>>3));
  int bxi, byi;
  if (gx <= gy){ bxi = tile % gx; byi = tile / gx; }
  else         { byi = tile % gy; bxi = tile / gy; }
  const int bm = byi*BM, bn = bxi*BN;

  const int gz = blockIdx.z;
  W += (size_t)gz*wstride;
  const float* bias = (gz==0)? b0 : (gz==1)? b1 : b2;
  if (Cf) Cf += (size_t)gz*ostrideF;
  if (Cs) Cs += (size_t)gz*ostrideS;
  const int wm = (wave/NWX)*WM, wn = (wave%NWX)*WN;
  const int kbeg = kslice ? gz*kslice : 0;
  const int kend = kslice ? kbeg+kslice : K;

  // per-lane physical slot for logical plane p at this lane's row (row&7 == l16&7)
  int sa[4];
  #pragma unroll
  for (int p=0;p<4;p++) sa[p] = (((p&1)<<2) + quad) ^ (l16&7);

  auto STAGE = [&](int bsel, int k0){
    #pragma unroll
    for (int n=0;n<NPW;n++){
      int it = wave*NPW + n;
      const ushort* mat; long PS; int brow, pair, r0, lbase;
      if (it < BM/4){
        pair = it/(BM/8); r0 = (it%(BM/8))*8;
        mat = A; PS = PSa; brow = bm;
        lbase = (pair*BM + r0)*8;            // 16B units
      } else {
        int itb = it - BM/4;
        pair = itb/(BN/8); r0 = (itb%(BN/8))*8;
        mat = W; PS = PSw; brow = bn;
        lbase = (2*BM + pair*BN + r0)*8;
      }
      int row = r0 + lrow;
      int s = sl ^ (row&7);
      int plane = pair*2 + (s>>2);
      const ushort* gp = mat + (size_t)plane*PS + (size_t)(brow+row)*K + k0 + (s&3)*8;
      __builtin_amdgcn_global_load_lds(
          (const __attribute__((address_space(1))) void*)gp,
          (__attribute__((address_space(3))) void*)&lds[bsel*BUF + lbase*8], 16, 0, 0);
    }
  };
  auto WAITN = [&](){
    if constexpr (NPW==16)      asm volatile("s_waitcnt vmcnt(16)" ::: "memory");
    else if constexpr (NPW==12) asm volatile("s_waitcnt vmcnt(12)" ::: "memory");
    else                        asm volatile("s_waitcnt vmcnt(0)"  ::: "memory");
  };
  auto WAIT0 = [&](){ asm volatile("s_waitcnt vmcnt(0)" ::: "memory"); };
  auto BAR = [&](){
    asm volatile("" ::: "memory");
    __builtin_amdgcn_s_barrier();
    asm volatile("" ::: "memory");
  };

  f32x4 accr[NI][NJ], acci[NI][NJ];
  #pragma unroll
  for (int i=0;i<NI;i++)
    #pragma unroll
    for (int j=0;j<NJ;j++){
      accr[i][j] = (f32x4){0.f,0.f,0.f,0.f};
      acci[i][j] = (f32x4){0.f,0.f,0.f,0.f};
    }

  int cur = 0;
  STAGE(0, kbeg);
  if (kbeg+32 < kend) STAGE(1, kbeg+32);
  for (int k0=kbeg; k0<kend; k0+=32){
    if (k0+32 < kend) WAITN(); else WAIT0();   // buf[cur] landed; next stays in flight
    BAR();
    const int cb = cur*BUF;

    bf16x8 Bf[NJ][4];
    #pragma unroll
    for (int j=0;j<NJ;j++){
      int row = wn + j*16 + l16;
      #pragma unroll
      for (int p=0;p<4;p++)
        Bf[j][p] = *(const bf16x8*)&lds[cb + BM*128 + ((p>>1)*BN + row)*64 + sa[p]*8];
    }
    #pragma unroll
    for (int i=0;i<NI;i++){
      int row = wm + i*16 + l16;
      bf16x8 A0 = *(const bf16x8*)&lds[cb + (0*BM + row)*64 + sa[0]*8];
      bf16x8 A1 = *(const bf16x8*)&lds[cb + (0*BM + row)*64 + sa[1]*8];
      bf16x8 A2 = *(const bf16x8*)&lds[cb + (1*BM + row)*64 + sa[2]*8];
      bf16x8 A3 = *(const bf16x8*)&lds[cb + (1*BM + row)*64 + sa[3]*8];
      bf16x8 n2 = negv(A2), n3 = negv(A3);
      #pragma unroll
      for (int j=0;j<NJ;j++){
        f32x4 cr = accr[i][j], ci = acci[i][j];
        cr = mfma16(A0, Bf[j][0], cr); cr = mfma16(A0, Bf[j][1], cr); cr = mfma16(A1, Bf[j][0], cr);
        cr = mfma16(n2, Bf[j][2], cr); cr = mfma16(n2, Bf[j][3], cr); cr = mfma16(n3, Bf[j][2], cr);
        ci = mfma16(A0, Bf[j][2], ci); ci = mfma16(A0, Bf[j][3], ci); ci = mfma16(A1, Bf[j][2], ci);
        ci = mfma16(A2, Bf[j][0], ci); ci = mfma16(A2, Bf[j][1], ci); ci = mfma16(A3, Bf[j][0], ci);
        accr[i][j] = cr; acci[i][j] = ci;
      }
    }
    BAR();                                    // all waves done reading buf[cur]
    if (k0+64 < kend) STAGE(cur, k0+64);      // refill just-consumed buffer
    cur ^= 1;
  }
  #pragma unroll
  for (int i=0;i<NI;i++){
    #pragma unroll
    for (int j=0;j<NJ;j++){
      #pragma unroll
      for (int rg=0;rg<4;rg++){
        int row = bm + wm + i*16 + quad*4 + rg;
        int col = bn + wn + j*16 + l16;
        float br = 0.f, bi2 = 0.f;
        if (bias){
          br  = biasRow ? bias[row]   : bias[col];
          bi2 = biasRow ? bias[M+row] : bias[N+col];
        }
        float cr = accr[i][j][rg] + br;
        float ci = acci[i][j][rg] + bi2;
        size_t o = (size_t)row*N + col;
        if (Rr){ cr += Rr[o]; ci += Ri[o]; }
        if (relu){ cr = fmaxf(cr,0.f); ci = fmaxf(ci,0.f); }
        if (Cf){ Cf[o] = cr; Cf[PSc + o] = ci; }
        if (Cs){
          ushort h0,l0,h1v,l1;
          fsplit(cr,h0,l0); fsplit(ci,h1v,l1);
          Cs[o] = h0; Cs[PSs+o] = l0; Cs[2*PSs+o] = h1v; Cs[3*PSs+o] = l1;
        }
      }
    }
  }
}

// phasor table: tab[2*(t*64+d)] = cos, [+1] = sin
__global__ __launch_bounds__(256) void rope_table(float* __restrict__ tab){
  int i = blockIdx.x*256 + threadIdx.x;   // 0..65535
  int d = i & 63, t = i >> 6;
  float invf = expf(-(float)d * (9.210340371976184f/64.0f));
  float th = (float)t * invf;
  float s, c;
  sincosf(th, &s, &c);
  tab[2*i] = c; tab[2*i+1] = s;
}

// In-place RoPE on split-bf16 Q,K planes (PS = plane stride in ushorts).
__global__ __launch_bounds__(256) void rope_split(ushort* __restrict__ Q,
    ushort* __restrict__ Kk, const float* __restrict__ tab, long PS)
{
  size_t idx = (size_t)blockIdx.x*256 + threadIdx.x;
  int d = (int)(idx & (HD_-1));
  int t = (int)((idx >> 10) & (T_-1));
  float2 cs = *(const float2*)(tab + 2*(t*HD_ + d));
  float c = cs.x, s = cs.y;
  {
    float qr = b2f(Q[idx])      + b2f(Q[PS+idx]);
    float qi = b2f(Q[2*PS+idx]) + b2f(Q[3*PS+idx]);
    float nr = qr*c - qi*s, ni = qr*s + qi*c;
    ushort h,l;
    fsplit(nr,h,l); Q[idx]=h;      Q[PS+idx]=l;
    fsplit(ni,h,l); Q[2*PS+idx]=h; Q[3*PS+idx]=l;
  }
  {
    float kr = b2f(Kk[idx])      + b2f(Kk[PS+idx]);
    float ki = b2f(Kk[2*PS+idx]) + b2f(Kk[3*PS+idx]);
    float nr = kr*c - ki*s, ni = kr*s + ki*c;
    ushort h,l;
    fsplit(nr,h,l); Kk[idx]=h;      Kk[PS+idx]=l;
    fsplit(ni,h,l); Kk[2*PS+idx]=h; Kk[3*PS+idx]=l;
  }
}

// MFMA flash attention (full batch). Q,K: split-bf16 [4][4M] rows b*T+t.
// Vt: split-bf16 V^T [4][1024*4096] (rows h*64+d, cols b*T+t).
__global__ __launch_bounds__(256) void attn_mfma(
    const ushort* __restrict__ Qg, const ushort* __restrict__ Kg,
    const ushort* __restrict__ Vt, long PS,
    ushort* __restrict__ O, long PSo)
{
  __shared__ __align__(16) ushort lds[24576];
  const int tid = threadIdx.x;
  const int wave = tid>>6, lane = tid&63;
  const int quad = lane>>4, l16 = lane&15;
  const int bh = blockIdx.x, b = bh>>4, h = bh&15;
  const int y = blockIdx.y;
  const int qb = (y<8) ? (15-y) : (y-8);   // pair big+small blocks per CU
  const int qt0 = qb*64;
  const int qg = qt0 + wave*16 + l16;      // this lane's q row (softmax role)
  const int Pbase = 19456 + wave*1280;

  bf16x8 Qf[4][2];
  {
    size_t row = (size_t)(b*T_ + qt0 + wave*16 + l16);
    #pragma unroll
    for (int p=0;p<4;p++)
      #pragma unroll
      for (int dk=0;dk<2;dk++)
        Qf[p][dk] = *(const bf16x8*)(Qg + (size_t)p*PS + row*D_ + h*HD_ + dk*32 + quad*8);
  }
  f32x4 Or[4], Oi[4];
  #pragma unroll
  for (int dt=0;dt<4;dt++){ Or[dt]=(f32x4){0,0,0,0}; Oi[dt]=(f32x4){0,0,0,0}; }
  float mreg = -1e30f, lreg = 0.f;
  const int ntiles = 2*qb + 2;

  for (int tI=0; tI<ntiles; tI++){
    const int kt = tI*32;
    __syncthreads();
    #pragma unroll
    for (int r=0;r<4;r++){
      int id = r*256 + tid;
      int p = id>>8, rem = id&255;
      int row = rem>>3, slk = rem&7;
      const ushort* src = Kg + (size_t)p*PS + (size_t)(b*T_ + kt + row)*D_ + h*HD_ + slk*8;
      *(uint4*)&lds[p*2304 + row*72 + slk*8] = *(const uint4*)src;
    }
    {
      const ushort* srcp = Vt + (size_t)wave*PS + (size_t)(b*T_ + kt);
      #pragma unroll
      for (int r=0;r<4;r++){
        int chunk = r*64 + lane;
        int dd = chunk>>2, kg = chunk&3;
        *(uint4*)&lds[9216 + wave*2560 + dd*40 + kg*8] =
            *(const uint4*)(srcp + (size_t)(h*HD_ + dd)*BT_ + kg*8);
      }
    }
    __syncthreads();

    f32x4 sr[2], si[2];
    sr[0]=(f32x4){0,0,0,0}; sr[1]=(f32x4){0,0,0,0};
    si[0]=(f32x4){0,0,0,0}; si[1]=(f32x4){0,0,0,0};
    #pragma unroll
    for (int s=0;s<2;s++){
      #pragma unroll
      for (int dk=0;dk<2;dk++){
        int ra = (s*16+l16)*72 + dk*32 + quad*8;
        bf16x8 Krh = *(const bf16x8*)&lds[ra];
        bf16x8 Krl = *(const bf16x8*)&lds[2304 + ra];
        bf16x8 Kih = *(const bf16x8*)&lds[4608 + ra];
        bf16x8 Kil = *(const bf16x8*)&lds[6912 + ra];
        bf16x8 nKih = negv(Kih), nKil = negv(Kil);
        f32x4 r = sr[s], im = si[s];
        r = mfma16(Krh, Qf[0][dk], r); r = mfma16(Krh, Qf[1][dk], r); r = mfma16(Krl, Qf[0][dk], r);
        r = mfma16(Kih, Qf[2][dk], r); r = mfma16(Kih, Qf[3][dk], r); r = mfma16(Kil, Qf[2][dk], r);
        im = mfma16(Krh,  Qf[2][dk], im); im = mfma16(Krh,  Qf[3][dk], im); im = mfma16(Krl,  Qf[2][dk], im);
        im = mfma16(nKih, Qf[0][dk], im); im = mfma16(nKih, Qf[1][dk], im); im = mfma16(nKil, Qf[0][dk], im);
        sr[s]=r; si[s]=im;
      }
    }

    float pv[2][4];
    float mx = -1e30f;
    #pragma unroll
    for (int s=0;s<2;s++)
      #pragma unroll
      for (int rg=0;rg<4;rg++){
        float xr = sr[s][rg], xi = si[s][rg];
        float m = sqrtf(xr*xr + xi*xi)*0.125f;
        int kloc = kt + s*16 + quad*4 + rg;
        if (kloc > qg) m = -1e30f;
        pv[s][rg] = m;
        mx = fmaxf(mx, m);
      }
    mx = fmaxf(mx, __shfl_xor(mx,16));
    mx = fmaxf(mx, __shfl_xor(mx,32));
    float mnew = fmaxf(mreg, mx);
    float afac = __expf(mreg - mnew);
    float ps = 0.f;
    #pragma unroll
    for (int s=0;s<2;s++)
      #pragma unroll
      for (int rg=0;rg<4;rg++){
        float e = __expf(pv[s][rg] - mnew);
        pv[s][rg] = e; ps += e;
      }
    ps += __shfl_xor(ps,16); ps += __shfl_xor(ps,32);
    lreg = lreg*afac + ps;
    mreg = mnew;

    #pragma unroll
    for (int s=0;s<2;s++)
      #pragma unroll
      for (int rg=0;rg<4;rg++){
        ushort hi,lo; fsplit(pv[s][rg],hi,lo);
        int off = Pbase + l16*40 + s*16 + quad*4 + rg;
        lds[off] = hi; lds[off+640] = lo;
      }

    float af[4];
    #pragma unroll
    for (int rg=0;rg<4;rg++) af[rg] = __shfl(afac, quad*4+rg);
    #pragma unroll
    for (int dt=0;dt<4;dt++)
      #pragma unroll
      for (int rg=0;rg<4;rg++){ Or[dt][rg]*=af[rg]; Oi[dt][rg]*=af[rg]; }

    bf16x8 Ph  = *(const bf16x8*)&lds[Pbase +       l16*40 + quad*8];
    bf16x8 Plo = *(const bf16x8*)&lds[Pbase + 640 + l16*40 + quad*8];
    #pragma unroll
    for (int dt=0;dt<4;dt++){
      int rv = (dt*16+l16)*40 + quad*8;
      bf16x8 Vrh = *(const bf16x8*)&lds[9216 + rv];
      bf16x8 Vrl = *(const bf16x8*)&lds[9216 + 2560 + rv];
      bf16x8 Vih = *(const bf16x8*)&lds[9216 + 5120 + rv];
      bf16x8 Vil = *(const bf16x8*)&lds[9216 + 7680 + rv];
      f32x4 o_r = Or[dt], o_i = Oi[dt];
      o_r = mfma16(Ph, Vrh, o_r); o_r = mfma16(Ph, Vrl, o_r); o_r = mfma16(Plo, Vrh, o_r);
      o_i = mfma16(Ph, Vih, o_i); o_i = mfma16(Ph, Vil, o_i); o_i = mfma16(Plo, Vih, o_i);
      Or[dt]=o_r; Oi[dt]=o_i;
    }
  }

  float li[4];
  #pragma unroll
  for (int rg=0;rg<4;rg++) li[rg] = 1.0f / __shfl(lreg, quad*4+rg);
  #pragma unroll
  for (int dt=0;dt<4;dt++)
    #pragma unroll
    for (int rg=0;rg<4;rg++){
      float tr = Or[dt][rg]*li[rg], ti = Oi[dt][rg]*li[rg];
      ushort h0,l0,h1,l1;
      fsplit(tr,h0,l0); fsplit(ti,h1,l1);
      int rowt = qt0 + wave*16 + quad*4 + rg;
      size_t o = (size_t)(b*T_ + rowt)*D_ + h*HD_ + dt*16 + l16;
      O[o] = h0; O[PSo+o] = l0; O[2*PSo+o] = h1; O[3*PSo+o] = l1;
    }
}

// h = p0+p1 (f32 partials, bias already in p0) -> split-bf16 4 planes
__global__ __launch_bounds__(256) void hsum_kernel(const float* __restrict__ p0,
    const float* __restrict__ p1, ushort* __restrict__ out)
{
  size_t idx = (size_t)blockIdx.x*256 + threadIdx.x;
  const size_t M1s = (size_t)1<<20;
  float hr = p0[idx] + p1[idx];
  float hi = p0[M1s+idx] + p1[M1s+idx];
  ushort h0,l0,h1,l1;
  fsplit(hr,h0,l0); fsplit(hi,h1,l1);
  out[idx] = h0; out[M1s+idx] = l0; out[2*M1s+idx] = h1; out[3*M1s+idx] = l1;
}

// out = z + h * (g/(|g|+1e-8)); h split-4 planes; g = gp0+gp1 f32 partials.
__global__ __launch_bounds__(256) void gate_kernel(
    const float* __restrict__ z, const ushort* __restrict__ hB,
    const float* __restrict__ gp0, const float* __restrict__ gp1,
    float* __restrict__ out, int off)
{
  size_t idx = (size_t)blockIdx.x*256 + threadIdx.x;  // 0..1M
  const size_t M1 = (size_t)1<<20;
  float hr = b2f(hB[idx])      + b2f(hB[M1+idx]);
  float hi = b2f(hB[2*M1+idx]) + b2f(hB[3*M1+idx]);
  float gr = gp0[idx] + gp1[idx];
  float gi = gp0[M1+idx] + gp1[M1+idx];
  float gn = sqrtf(gr*gr + gi*gi) + 1e-8f;
  float pr = (hr*gr - hi*gi) / gn;
  float pi = (hr*gi + hi*gr) / gn;
  size_t zoff = (size_t)off + idx;
  out[zoff]    = z[zoff] + pr;
  out[PL+zoff] = z[PL+zoff] + pi;
}

extern "C" void kernel_launch(void* const* d_in, const int* in_sizes, int n_in,
                              void* d_out, int out_size, void* d_ws, size_t ws_size,
                              hipStream_t stream)
{
  const float* x  = (const float*)d_in[0];
  const float* wq = (const float*)d_in[2];
  const float* bq = (const float*)d_in[3];
  const float* wk = (const float*)d_in[4];
  const float* bk = (const float*)d_in[5];
  const float* wv = (const float*)d_in[6];
  const float* bv = (const float*)d_in[7];
  const float* wo = (const float*)d_in[8];
  const float* bo = (const float*)d_in[9];
  const float* wf1= (const float*)d_in[10];
  const float* bf1= (const float*)d_in[11];
  const float* wf2= (const float*)d_in[12];
  const float* bf2= (const float*)d_in[13];
  const float* wg = (const float*)d_in[14];
  const float* bg = (const float*)d_in[15];
  const float* g1 = (const float*)d_in[16];
  const float* b1 = (const float*)d_in[17];
  const float* g2 = (const float*)d_in[18];
  const float* b2 = (const float*)d_in[19];
  float* out = (float*)d_out;
  char* w8 = (char*)d_ws;
  const size_t MB = (size_t)1<<20;
  const long M1 = 1L<<20, M4 = 1L<<22;

  // ---- attention-phase layout (full-M, no chunking) ----
  ushort* wqkvB = (ushort*)(w8);             // [3][4][1M] us, 24MB
  ushort* woB   = (ushort*)(w8 + 24*MB);     // [4][1M] us, 8MB
  ushort* nzB   = (ushort*)(w8 + 32*MB);     // [4][4M] us, 32MB
  ushort* qS    = (ushort*)(w8 + 64*MB);     // [4][4M] us, 32MB
  ushort* kS    = (ushort*)(w8 + 96*MB);     // [4][4M] us, 32MB
  ushort* vtS   = (ushort*)(w8 + 128*MB);    // [4][4M] us, 32MB (V^T [1024][4096])
  float*  ropeT = (float*)(w8 + 32*MB);      // 512KB phasor table (over dead nzB)
  ushort* oBc   = (ushort*)(w8 + 32*MB);     // [4][4M] us (over nzB, dead)
  float*  z     = (float*)(w8 + 64*MB);      // [2][4M] f32 (over qS, dead)
  // ---- FFN-phase layout ----
  ushort* wf2B  = (ushort*)(w8);             // 32MB (over wqkvB+woB)
  ushort* h1c   = (ushort*)(w8 + 32*MB);     // [4][4M] us (over oBc)
  ushort* wf1B  = (ushort*)(w8 + 96*MB);     // 32MB (over kS)
  ushort* wgB   = (ushort*)(w8 + 128*MB);    // 8MB (over vtS)
  ushort* nz2c  = (ushort*)(w8 + 136*MB);    // [4][1M] us (8MB)
  float*  p0F   = (float*)(w8 + 136*MB);     // f32 [2][1M] partial 0 (alias nz2c)
  ushort* hBc   = (ushort*)(w8 + 144*MB);    // [4][1M] us (8MB)
  float*  p1F   = (float*)(w8 + 152*MB);     // f32 [2][1M] partial 1

  dim3 blk(256);
  // ---- attention branch ----
  cvt_split<<<1024, blk, 0, stream>>>(wq, wqkvB,        M1);
  cvt_split<<<1024, blk, 0, stream>>>(wk, wqkvB + 4*M1, M1);
  cvt_split<<<1024, blk, 0, stream>>>(wv, wqkvB + 8*M1, M1);
  cvt_split<<<1024, blk, 0, stream>>>(wo, woB,          M1);
  cln_kernel<<<dim3(BT_,2), blk, 0, stream>>>(x, (long)PL, 0, g1, b1, nzB, M4);
  // Q,K = nz @ {wq,wk}^T + b  (gz = weight set), full M=4096
  cgemm_split<128,128,64,64><<<dim3(8,32,2), blk, 0, stream>>>(
      nzB, M4, wqkvB, M1, 4*M1, bq, bk, nullptr,
      nullptr, nullptr, nullptr, 0, 0, qS, M4, 4*M4,
      4096, 1024, 1024, 0, 0, 0);
  // V^T = wv @ nz^T + bv(row): [1024 d][4096 t]
  cgemm_split<128,128,64,64><<<dim3(32,8,1), blk, 0, stream>>>(
      wqkvB + 8*M1, M1, nzB, M4, 0, bv, nullptr, nullptr,
      nullptr, nullptr, nullptr, 0, 0, vtS, M4, 0,
      1024, 4096, 1024, 0, 1, 0);
  rope_table<<<256, blk, 0, stream>>>(ropeT);
  rope_split<<<16384, blk, 0, stream>>>(qS, kS, ropeT, M4);
  attn_mfma<<<dim3(64,16), blk, 0, stream>>>(qS, kS, vtS, M4, oBc, M4);
  // z = o @ wo^T + bo + x (residual), full M=4096
  cgemm_split<128,128,64,64><<<dim3(8,32,1), blk, 0, stream>>>(
      oBc, M4, woB, M1, 0, bo, nullptr, nullptr,
      x, x + PL, z, (long)PL, 0, nullptr, 0, 0,
      4096, 1024, 1024, 0, 0, 0);
  // ---- FFN branch ----
  cvt_split<<<4096, blk, 0, stream>>>(wf1, wf1B, M4);
  cvt_split<<<4096, blk, 0, stream>>>(wf2, wf2B, M4);
  cvt_split<<<1024, blk, 0, stream>>>(wg, wgB, M1);
  for (int c=0; c<4; c++){
    cln_kernel<<<dim3(1024,2), blk, 0, stream>>>(z, (long)PL, c*1024, g2, b2, nz2c, M1);
    cgemm_split<128,128,64,64><<<dim3(32,8,1), blk, 0, stream>>>(
        nz2c, M1, wf1B, M4, 0, bf1, nullptr, nullptr,
        nullptr, nullptr, nullptr, 0, 0, h1c, M4, 0,
        1024, 4096, 1024, 1, 0, 0);
    // wf2: split-K=2 over K=4096; f32 partials p0 (bias) / p1
    cgemm_split<128,64,64,32><<<dim3(16,8,2), blk, 0, stream>>>(
        h1c, M4, wf2B, M4, 0, bf2, nullptr, nullptr,
        nullptr, nullptr, p0F, M1, M4, nullptr, 0, 0,
        1024, 1024, 4096, 0, 0, 2048);
    hsum_kernel<<<4096, blk, 0, stream>>>(p0F, p1F, hBc);
    // wg: split-K=2 over K=1024; partials p0 (bias bg) / p1
    cgemm_split<128,64,64,32><<<dim3(16,8,2), blk, 0, stream>>>(
        hBc, M1, wgB, M1, 0, bg, nullptr, nullptr,
        nullptr, nullptr, p0F, M1, M4, nullptr, 0, 0,
        1024, 1024, 1024, 0, 0, 512);
    gate_kernel<<<4096, blk, 0, stream>>>(z, hBc, p0F, p1F, out, c*(int)M1);
  }
}

// Round 6
// 1786.626 us; speedup vs baseline: 1.0689x; 1.0689x over previous
//
#include <hip/hip_runtime.h>
#include <math.h>

#define B_ 4
#define T_ 1024
#define D_ 1024
#define H_ 16
#define DFF_ 4096
#define HD_ 64
#define BT_ (B_*T_)
#define PL ((size_t)BT_*D_)   /* elements per fp32 component plane (4M) */

typedef unsigned int uint;
typedef unsigned short ushort;
typedef __attribute__((ext_vector_type(8))) __bf16 bf16x8;
typedef __attribute__((ext_vector_type(4))) float f32x4;
typedef __attribute__((ext_vector_type(4))) uint uint4v;

__device__ __forceinline__ float b2f(ushort u){
  union{uint i; float f;} x; x.i = ((uint)u)<<16; return x.f;
}
__device__ __forceinline__ ushort f2b(float f){
  union{float f; uint i;} x; x.f = f;
  uint r = x.i + 0x7fffu + ((x.i>>16)&1u);
  return (ushort)(r>>16);
}
__device__ __forceinline__ void fsplit(float x, ushort& hi, ushort& lo){
  hi = f2b(x);
  lo = f2b(x - b2f(hi));   // x - hi exact in fp32
}
__device__ __forceinline__ bf16x8 negv(bf16x8 v){
  union{bf16x8 b; uint4v u;} t; t.b = v;
  t.u ^= 0x80008000u;
  return t.b;
}
__device__ __forceinline__ f32x4 mfma16(bf16x8 a, bf16x8 b, f32x4 c){
  return __builtin_amdgcn_mfma_f32_16x16x32_bf16(a,b,c,0,0,0);
}
__device__ __forceinline__ float block_sum(float v, float* sm){
  #pragma unroll
  for (int o=32;o>0;o>>=1) v += __shfl_down(v,o);
  int wid = threadIdx.x>>6;
  if ((threadIdx.x&63)==0) sm[wid]=v;
  __syncthreads();
  float r = sm[0]+sm[1]+sm[2]+sm[3];
  __syncthreads();
  return r;
}

// fp32 complex weight [2][NK] -> split-bf16 [4][NK] (rh, rl, ih, il)
__global__ __launch_bounds__(256) void cvt_split(const float* __restrict__ s,
                                                 ushort* __restrict__ d, long NK){
  long i = ((long)blockIdx.x*256 + threadIdx.x)*4;
  if (i >= NK) return;
  float4 vr = *(const float4*)(s+i);
  float4 vi = *(const float4*)(s+NK+i);
  ushort4 rh, rl, ih4, il4;
  fsplit(vr.x, rh.x, rl.x); fsplit(vr.y, rh.y, rl.y);
  fsplit(vr.z, rh.z, rl.z); fsplit(vr.w, rh.w, rl.w);
  fsplit(vi.x, ih4.x, il4.x); fsplit(vi.y, ih4.y, il4.y);
  fsplit(vi.z, ih4.z, il4.z); fsplit(vi.w, ih4.w, il4.w);
  *(ushort4*)(d + i)        = rh;
  *(ushort4*)(d + NK + i)   = rl;
  *(ushort4*)(d + 2*NK + i) = ih4;
  *(ushort4*)(d + 3*NK + i) = il4;
}

// Per-component LayerNorm over D; fp32 in, split-bf16 out (4 planes).
__global__ __launch_bounds__(256) void cln_kernel(const float* __restrict__ x,
    long PSx, int row0, const float* __restrict__ g, const float* __restrict__ bb,
    ushort* __restrict__ out, long PSo)
{
  __shared__ float sm[4];
  int row = blockIdx.x, comp = blockIdx.y;
  const float* xr = x + (size_t)comp*PSx + (size_t)(row0+row)*D_;
  float4 v = *(const float4*)(xr + threadIdx.x*4);
  float s = v.x+v.y+v.z+v.w;
  s = block_sum(s, sm);
  float mean = s * (1.0f/D_);
  float dx=v.x-mean, dy=v.y-mean, dz=v.z-mean, dw=v.w-mean;
  float s2 = dx*dx+dy*dy+dz*dz+dw*dw;
  s2 = block_sum(s2, sm);
  float inv = 1.0f/sqrtf(s2*(1.0f/D_) + 1e-5f);
  float4 gv = *(const float4*)(g + comp*D_ + threadIdx.x*4);
  float4 bv = *(const float4*)(bb + comp*D_ + threadIdx.x*4);
  float y0 = dx*inv*gv.x + bv.x, y1 = dy*inv*gv.y + bv.y;
  float y2 = dz*inv*gv.z + bv.z, y3 = dw*inv*gv.w + bv.w;
  ushort4 hh, ll;
  fsplit(y0, hh.x, ll.x); fsplit(y1, hh.y, ll.y);
  fsplit(y2, hh.z, ll.z); fsplit(y3, hh.w, ll.w);
  ushort* oh = out + (size_t)(comp*2)*PSo   + (size_t)row*D_;
  ushort* ol = out + (size_t)(comp*2+1)*PSo + (size_t)row*D_;
  *(ushort4*)(oh + threadIdx.x*4) = hh;
  *(ushort4*)(ol + threadIdx.x*4) = ll;
}

// Split-bf16 complex MFMA GEMM: C = A @ W^T + bias (+res) (opt CReLU).
// Double-buffered LDS with depth-2 counted-vmcnt pipeline; NT threads
// (NT=512 -> 8 waves, 2 waves/SIMD for latency hiding). Raw s_barrier,
// s_waitcnt vmcnt(NPW) waits only for the stage issued 2 steps ago.
// XCD-chunked tile remap. LDS per buffer: per matrix 2 plane-pairs;
// row of 8 16B slots, physical slot = logical ^ (row&7).
template<int BM,int BN,int WM,int WN,int NT>
__global__ __launch_bounds__(NT,1) void cgemm_split(
    const ushort* __restrict__ A, long PSa,
    const ushort* __restrict__ W, long PSw, long wstride,
    const float* b0, const float* b1, const float* b2,
    const float* __restrict__ Rr, const float* __restrict__ Ri,
    float* __restrict__ Cf, long PSc, long ostrideF,
    ushort* __restrict__ Cs, long PSs, long ostrideS,
    int M, int N, int K, int relu, int biasRow, int kslice)
{
  constexpr int NI = WM/16, NJ = WN/16;
  constexpr int NWX = BN/WN;
  constexpr int NPW = (BM+BN)*16/NT;  // global_load_lds per wave per K-step
  constexpr int BUF = (BM+BN)*128;    // ushorts per buffer
  __shared__ __align__(16) ushort lds[2*BUF];
  const int tid = threadIdx.x, wave = tid>>6, lane = tid&63;
  const int quad = lane>>4, l16 = lane&15;
  const int lrow = lane>>3, sl = lane&7;

  // XCD-chunked bijective tile remap (nt % 8 == 0 at all call sites)
  const int gx = gridDim.x, gy = gridDim.y;
  const int nt = gx*gy;
  int lin = blockIdx.x + gx*blockIdx.y;
  int tile = (nt&7) ? lin : ((lin&7)*(nt>>3) + (lin>>3));
  int bxi, byi;
  if (gx <= gy){ bxi = tile % gx; byi = tile / gx; }
  else         { byi = tile % gy; bxi = tile / gy; }
  const int bm = byi*BM, bn = bxi*BN;

  const int gz = blockIdx.z;
  W += (size_t)gz*wstride;
  const float* bias = (gz==0)? b0 : (gz==1)? b1 : b2;
  if (Cf) Cf += (size_t)gz*ostrideF;
  if (Cs) Cs += (size_t)gz*ostrideS;
  const int wm = (wave/NWX)*WM, wn = (wave%NWX)*WN;
  const int kbeg = kslice ? gz*kslice : 0;
  const int kend = kslice ? kbeg+kslice : K;

  // per-lane physical slot for logical plane p at this lane's row (row&7 == l16&7)
  int sa[4];
  #pragma unroll
  for (int p=0;p<4;p++) sa[p] = (((p&1)<<2) + quad) ^ (l16&7);

  auto STAGE = [&](int bsel, int k0){
    #pragma unroll
    for (int n=0;n<NPW;n++){
      int it = wave*NPW + n;
      const ushort* mat; long PS; int brow, pair, r0, lbase;
      if (it < BM/4){
        pair = it/(BM/8); r0 = (it%(BM/8))*8;
        mat = A; PS = PSa; brow = bm;
        lbase = (pair*BM + r0)*8;            // 16B units
      } else {
        int itb = it - BM/4;
        pair = itb/(BN/8); r0 = (itb%(BN/8))*8;
        mat = W; PS = PSw; brow = bn;
        lbase = (2*BM + pair*BN + r0)*8;
      }
      int row = r0 + lrow;
      int s = sl ^ (row&7);
      int plane = pair*2 + (s>>2);
      const ushort* gp = mat + (size_t)plane*PS + (size_t)(brow+row)*K + k0 + (s&3)*8;
      __builtin_amdgcn_global_load_lds(
          (const __attribute__((address_space(1))) void*)gp,
          (__attribute__((address_space(3))) void*)&lds[bsel*BUF + lbase*8], 16, 0, 0);
    }
  };
  auto WAITN = [&](){
    if constexpr (NPW==16)      asm volatile("s_waitcnt vmcnt(16)" ::: "memory");
    else if constexpr (NPW==12) asm volatile("s_waitcnt vmcnt(12)" ::: "memory");
    else if constexpr (NPW==8)  asm volatile("s_waitcnt vmcnt(8)"  ::: "memory");
    else                        asm volatile("s_waitcnt vmcnt(0)"  ::: "memory");
  };
  auto WAIT0 = [&](){ asm volatile("s_waitcnt vmcnt(0)" ::: "memory"); };
  auto BAR = [&](){
    asm volatile("" ::: "memory");
    __builtin_amdgcn_s_barrier();
    asm volatile("" ::: "memory");
  };

  f32x4 accr[NI][NJ], acci[NI][NJ];
  #pragma unroll
  for (int i=0;i<NI;i++)
    #pragma unroll
    for (int j=0;j<NJ;j++){
      accr[i][j] = (f32x4){0.f,0.f,0.f,0.f};
      acci[i][j] = (f32x4){0.f,0.f,0.f,0.f};
    }

  int cur = 0;
  STAGE(0, kbeg);
  if (kbeg+32 < kend) STAGE(1, kbeg+32);
  for (int k0=kbeg; k0<kend; k0+=32){
    if (k0+32 < kend) WAITN(); else WAIT0();   // buf[cur] landed; next stays in flight
    BAR();
    const int cb = cur*BUF;

    bf16x8 Bf[NJ][4];
    #pragma unroll
    for (int j=0;j<NJ;j++){
      int row = wn + j*16 + l16;
      #pragma unroll
      for (int p=0;p<4;p++)
        Bf[j][p] = *(const bf16x8*)&lds[cb + BM*128 + ((p>>1)*BN + row)*64 + sa[p]*8];
    }
    #pragma unroll
    for (int i=0;i<NI;i++){
      int row = wm + i*16 + l16;
      bf16x8 A0 = *(const bf16x8*)&lds[cb + (0*BM + row)*64 + sa[0]*8];
      bf16x8 A1 = *(const bf16x8*)&lds[cb + (0*BM + row)*64 + sa[1]*8];
      bf16x8 A2 = *(const bf16x8*)&lds[cb + (1*BM + row)*64 + sa[2]*8];
      bf16x8 A3 = *(const bf16x8*)&lds[cb + (1*BM + row)*64 + sa[3]*8];
      bf16x8 n2 = negv(A2), n3 = negv(A3);
      #pragma unroll
      for (int j=0;j<NJ;j++){
        f32x4 cr = accr[i][j], ci = acci[i][j];
        cr = mfma16(A0, Bf[j][0], cr); cr = mfma16(A0, Bf[j][1], cr); cr = mfma16(A1, Bf[j][0], cr);
        cr = mfma16(n2, Bf[j][2], cr); cr = mfma16(n2, Bf[j][3], cr); cr = mfma16(n3, Bf[j][2], cr);
        ci = mfma16(A0, Bf[j][2], ci); ci = mfma16(A0, Bf[j][3], ci); ci = mfma16(A1, Bf[j][2], ci);
        ci = mfma16(A2, Bf[j][0], ci); ci = mfma16(A2, Bf[j][1], ci); ci = mfma16(A3, Bf[j][0], ci);
        accr[i][j] = cr; acci[i][j] = ci;
      }
    }
    BAR();                                    // all waves done reading buf[cur]
    if (k0+64 < kend) STAGE(cur, k0+64);      // refill just-consumed buffer
    cur ^= 1;
  }
  #pragma unroll
  for (int i=0;i<NI;i++){
    #pragma unroll
    for (int j=0;j<NJ;j++){
      #pragma unroll
      for (int rg=0;rg<4;rg++){
        int row = bm + wm + i*16 + quad*4 + rg;
        int col = bn + wn + j*16 + l16;
        float br = 0.f, bi2 = 0.f;
        if (bias){
          br  = biasRow ? bias[row]   : bias[col];
          bi2 = biasRow ? bias[M+row] : bias[N+col];
        }
        float cr = accr[i][j][rg] + br;
        float ci = acci[i][j][rg] + bi2;
        size_t o = (size_t)row*N + col;
        if (Rr){ cr += Rr[o]; ci += Ri[o]; }
        if (relu){ cr = fmaxf(cr,0.f); ci = fmaxf(ci,0.f); }
        if (Cf){ Cf[o] = cr; Cf[PSc + o] = ci; }
        if (Cs){
          ushort h0,l0,h1v,l1;
          fsplit(cr,h0,l0); fsplit(ci,h1v,l1);
          Cs[o] = h0; Cs[PSs+o] = l0; Cs[2*PSs+o] = h1v; Cs[3*PSs+o] = l1;
        }
      }
    }
  }
}

// phasor table: tab[2*(t*64+d)] = cos, [+1] = sin
__global__ __launch_bounds__(256) void rope_table(float* __restrict__ tab){
  int i = blockIdx.x*256 + threadIdx.x;   // 0..65535
  int d = i & 63, t = i >> 6;
  float invf = expf(-(float)d * (9.210340371976184f/64.0f));
  float th = (float)t * invf;
  float s, c;
  sincosf(th, &s, &c);
  tab[2*i] = c; tab[2*i+1] = s;
}

// In-place RoPE on split-bf16 Q,K planes (PS = plane stride in ushorts).
__global__ __launch_bounds__(256) void rope_split(ushort* __restrict__ Q,
    ushort* __restrict__ Kk, const float* __restrict__ tab, long PS)
{
  size_t idx = (size_t)blockIdx.x*256 + threadIdx.x;
  int d = (int)(idx & (HD_-1));
  int t = (int)((idx >> 10) & (T_-1));
  float2 cs = *(const float2*)(tab + 2*(t*HD_ + d));
  float c = cs.x, s = cs.y;
  {
    float qr = b2f(Q[idx])      + b2f(Q[PS+idx]);
    float qi = b2f(Q[2*PS+idx]) + b2f(Q[3*PS+idx]);
    float nr = qr*c - qi*s, ni = qr*s + qi*c;
    ushort h,l;
    fsplit(nr,h,l); Q[idx]=h;      Q[PS+idx]=l;
    fsplit(ni,h,l); Q[2*PS+idx]=h; Q[3*PS+idx]=l;
  }
  {
    float kr = b2f(Kk[idx])      + b2f(Kk[PS+idx]);
    float ki = b2f(Kk[2*PS+idx]) + b2f(Kk[3*PS+idx]);
    float nr = kr*c - ki*s, ni = kr*s + ki*c;
    ushort h,l;
    fsplit(nr,h,l); Kk[idx]=h;      Kk[PS+idx]=l;
    fsplit(ni,h,l); Kk[2*PS+idx]=h; Kk[3*PS+idx]=l;
  }
}

// MFMA flash attention (full batch). Q,K: split-bf16 [4][4M] rows b*T+t.
// Vt: split-bf16 V^T [4][1024*4096] (rows h*64+d, cols b*T+t).
__global__ __launch_bounds__(256) void attn_mfma(
    const ushort* __restrict__ Qg, const ushort* __restrict__ Kg,
    const ushort* __restrict__ Vt, long PS,
    ushort* __restrict__ O, long PSo)
{
  __shared__ __align__(16) ushort lds[24576];
  const int tid = threadIdx.x;
  const int wave = tid>>6, lane = tid&63;
  const int quad = lane>>4, l16 = lane&15;
  const int bh = blockIdx.x, b = bh>>4, h = bh&15;
  const int y = blockIdx.y;
  const int qb = (y<8) ? (15-y) : (y-8);   // pair big+small blocks per CU
  const int qt0 = qb*64;
  const int qg = qt0 + wave*16 + l16;      // this lane's q row (softmax role)
  const int Pbase = 19456 + wave*1280;

  bf16x8 Qf[4][2];
  {
    size_t row = (size_t)(b*T_ + qt0 + wave*16 + l16);
    #pragma unroll
    for (int p=0;p<4;p++)
      #pragma unroll
      for (int dk=0;dk<2;dk++)
        Qf[p][dk] = *(const bf16x8*)(Qg + (size_t)p*PS + row*D_ + h*HD_ + dk*32 + quad*8);
  }
  f32x4 Or[4], Oi[4];
  #pragma unroll
  for (int dt=0;dt<4;dt++){ Or[dt]=(f32x4){0,0,0,0}; Oi[dt]=(f32x4){0,0,0,0}; }
  float mreg = -1e30f, lreg = 0.f;
  const int ntiles = 2*qb + 2;

  for (int tI=0; tI<ntiles; tI++){
    const int kt = tI*32;
    __syncthreads();
    #pragma unroll
    for (int r=0;r<4;r++){
      int id = r*256 + tid;
      int p = id>>8, rem = id&255;
      int row = rem>>3, slk = rem&7;
      const ushort* src = Kg + (size_t)p*PS + (size_t)(b*T_ + kt + row)*D_ + h*HD_ + slk*8;
      *(uint4*)&lds[p*2304 + row*72 + slk*8] = *(const uint4*)src;
    }
    {
      const ushort* srcp = Vt + (size_t)wave*PS + (size_t)(b*T_ + kt);
      #pragma unroll
      for (int r=0;r<4;r++){
        int chunk = r*64 + lane;
        int dd = chunk>>2, kg = chunk&3;
        *(uint4*)&lds[9216 + wave*2560 + dd*40 + kg*8] =
            *(const uint4*)(srcp + (size_t)(h*HD_ + dd)*BT_ + kg*8);
      }
    }
    __syncthreads();

    f32x4 sr[2], si[2];
    sr[0]=(f32x4){0,0,0,0}; sr[1]=(f32x4){0,0,0,0};
    si[0]=(f32x4){0,0,0,0}; si[1]=(f32x4){0,0,0,0};
    #pragma unroll
    for (int s=0;s<2;s++){
      #pragma unroll
      for (int dk=0;dk<2;dk++){
        int ra = (s*16+l16)*72 + dk*32 + quad*8;
        bf16x8 Krh = *(const bf16x8*)&lds[ra];
        bf16x8 Krl = *(const bf16x8*)&lds[2304 + ra];
        bf16x8 Kih = *(const bf16x8*)&lds[4608 + ra];
        bf16x8 Kil = *(const bf16x8*)&lds[6912 + ra];
        bf16x8 nKih = negv(Kih), nKil = negv(Kil);
        f32x4 r = sr[s], im = si[s];
        r = mfma16(Krh, Qf[0][dk], r); r = mfma16(Krh, Qf[1][dk], r); r = mfma16(Krl, Qf[0][dk], r);
        r = mfma16(Kih, Qf[2][dk], r); r = mfma16(Kih, Qf[3][dk], r); r = mfma16(Kil, Qf[2][dk], r);
        im = mfma16(Krh,  Qf[2][dk], im); im = mfma16(Krh,  Qf[3][dk], im); im = mfma16(Krl,  Qf[2][dk], im);
        im = mfma16(nKih, Qf[0][dk], im); im = mfma16(nKih, Qf[1][dk], im); im = mfma16(nKil, Qf[0][dk], im);
        sr[s]=r; si[s]=im;
      }
    }

    float pv[2][4];
    float mx = -1e30f;
    #pragma unroll
    for (int s=0;s<2;s++)
      #pragma unroll
      for (int rg=0;rg<4;rg++){
        float xr = sr[s][rg], xi = si[s][rg];
        float m = sqrtf(xr*xr + xi*xi)*0.125f;
        int kloc = kt + s*16 + quad*4 + rg;
        if (kloc > qg) m = -1e30f;
        pv[s][rg] = m;
        mx = fmaxf(mx, m);
      }
    mx = fmaxf(mx, __shfl_xor(mx,16));
    mx = fmaxf(mx, __shfl_xor(mx,32));
    float mnew = fmaxf(mreg, mx);
    float afac = __expf(mreg - mnew);
    float ps = 0.f;
    #pragma unroll
    for (int s=0;s<2;s++)
      #pragma unroll
      for (int rg=0;rg<4;rg++){
        float e = __expf(pv[s][rg] - mnew);
        pv[s][rg] = e; ps += e;
      }
    ps += __shfl_xor(ps,16); ps += __shfl_xor(ps,32);
    lreg = lreg*afac + ps;
    mreg = mnew;

    #pragma unroll
    for (int s=0;s<2;s++)
      #pragma unroll
      for (int rg=0;rg<4;rg++){
        ushort hi,lo; fsplit(pv[s][rg],hi,lo);
        int off = Pbase + l16*40 + s*16 + quad*4 + rg;
        lds[off] = hi; lds[off+640] = lo;
      }

    float af[4];
    #pragma unroll
    for (int rg=0;rg<4;rg++) af[rg] = __shfl(afac, quad*4+rg);
    #pragma unroll
    for (int dt=0;dt<4;dt++)
      #pragma unroll
      for (int rg=0;rg<4;rg++){ Or[dt][rg]*=af[rg]; Oi[dt][rg]*=af[rg]; }

    bf16x8 Ph  = *(const bf16x8*)&lds[Pbase +       l16*40 + quad*8];
    bf16x8 Plo = *(const bf16x8*)&lds[Pbase + 640 + l16*40 + quad*8];
    #pragma unroll
    for (int dt=0;dt<4;dt++){
      int rv = (dt*16+l16)*40 + quad*8;
      bf16x8 Vrh = *(const bf16x8*)&lds[9216 + rv];
      bf16x8 Vrl = *(const bf16x8*)&lds[9216 + 2560 + rv];
      bf16x8 Vih = *(const bf16x8*)&lds[9216 + 5120 + rv];
      bf16x8 Vil = *(const bf16x8*)&lds[9216 + 7680 + rv];
      f32x4 o_r = Or[dt], o_i = Oi[dt];
      o_r = mfma16(Ph, Vrh, o_r); o_r = mfma16(Ph, Vrl, o_r); o_r = mfma16(Plo, Vrh, o_r);
      o_i = mfma16(Ph, Vih, o_i); o_i = mfma16(Ph, Vil, o_i); o_i = mfma16(Plo, Vih, o_i);
      Or[dt]=o_r; Oi[dt]=o_i;
    }
  }

  float li[4];
  #pragma unroll
  for (int rg=0;rg<4;rg++) li[rg] = 1.0f / __shfl(lreg, quad*4+rg);
  #pragma unroll
  for (int dt=0;dt<4;dt++)
    #pragma unroll
    for (int rg=0;rg<4;rg++){
      float tr = Or[dt][rg]*li[rg], ti = Oi[dt][rg]*li[rg];
      ushort h0,l0,h1,l1;
      fsplit(tr,h0,l0); fsplit(ti,h1,l1);
      int rowt = qt0 + wave*16 + quad*4 + rg;
      size_t o = (size_t)(b*T_ + rowt)*D_ + h*HD_ + dt*16 + l16;
      O[o] = h0; O[PSo+o] = l0; O[2*PSo+o] = h1; O[3*PSo+o] = l1;
    }
}

// h = p0+p1 (f32 partials, bias already in p0) -> split-bf16 4 planes
__global__ __launch_bounds__(256) void hsum_kernel(const float* __restrict__ p0,
    const float* __restrict__ p1, ushort* __restrict__ out)
{
  size_t idx = (size_t)blockIdx.x*256 + threadIdx.x;
  const size_t M1s = (size_t)1<<20;
  float hr = p0[idx] + p1[idx];
  float hi = p0[M1s+idx] + p1[M1s+idx];
  ushort h0,l0,h1,l1;
  fsplit(hr,h0,l0); fsplit(hi,h1,l1);
  out[idx] = h0; out[M1s+idx] = l0; out[2*M1s+idx] = h1; out[3*M1s+idx] = l1;
}

// out = z + h * (g/(|g|+1e-8)); h split-4 planes; g = gp0+gp1 f32 partials.
__global__ __launch_bounds__(256) void gate_kernel(
    const float* __restrict__ z, const ushort* __restrict__ hB,
    const float* __restrict__ gp0, const float* __restrict__ gp1,
    float* __restrict__ out, int off)
{
  size_t idx = (size_t)blockIdx.x*256 + threadIdx.x;  // 0..1M
  const size_t M1 = (size_t)1<<20;
  float hr = b2f(hB[idx])      + b2f(hB[M1+idx]);
  float hi = b2f(hB[2*M1+idx]) + b2f(hB[3*M1+idx]);
  float gr = gp0[idx] + gp1[idx];
  float gi = gp0[M1+idx] + gp1[M1+idx];
  float gn = sqrtf(gr*gr + gi*gi) + 1e-8f;
  float pr = (hr*gr - hi*gi) / gn;
  float pi = (hr*gi + hi*gr) / gn;
  size_t zoff = (size_t)off + idx;
  out[zoff]    = z[zoff] + pr;
  out[PL+zoff] = z[PL+zoff] + pi;
}

extern "C" void kernel_launch(void* const* d_in, const int* in_sizes, int n_in,
                              void* d_out, int out_size, void* d_ws, size_t ws_size,
                              hipStream_t stream)
{
  const float* x  = (const float*)d_in[0];
  const float* wq = (const float*)d_in[2];
  const float* bq = (const float*)d_in[3];
  const float* wk = (const float*)d_in[4];
  const float* bk = (const float*)d_in[5];
  const float* wv = (const float*)d_in[6];
  const float* bv = (const float*)d_in[7];
  const float* wo = (const float*)d_in[8];
  const float* bo = (const float*)d_in[9];
  const float* wf1= (const float*)d_in[10];
  const float* bf1= (const float*)d_in[11];
  const float* wf2= (const float*)d_in[12];
  const float* bf2= (const float*)d_in[13];
  const float* wg = (const float*)d_in[14];
  const float* bg = (const float*)d_in[15];
  const float* g1 = (const float*)d_in[16];
  const float* b1 = (const float*)d_in[17];
  const float* g2 = (const float*)d_in[18];
  const float* b2 = (const float*)d_in[19];
  float* out = (float*)d_out;
  char* w8 = (char*)d_ws;
  const size_t MB = (size_t)1<<20;
  const long M1 = 1L<<20, M4 = 1L<<22;

  // ---- attention-phase layout (full-M, no chunking) ----
  ushort* wqkvB = (ushort*)(w8);             // [3][4][1M] us, 24MB
  ushort* woB   = (ushort*)(w8 + 24*MB);     // [4][1M] us, 8MB
  ushort* nzB   = (ushort*)(w8 + 32*MB);     // [4][4M] us, 32MB
  ushort* qS    = (ushort*)(w8 + 64*MB);     // [4][4M] us, 32MB
  ushort* kS    = (ushort*)(w8 + 96*MB);     // [4][4M] us, 32MB
  ushort* vtS   = (ushort*)(w8 + 128*MB);    // [4][4M] us, 32MB (V^T [1024][4096])
  float*  ropeT = (float*)(w8 + 32*MB);      // 512KB phasor table (over dead nzB)
  ushort* oBc   = (ushort*)(w8 + 32*MB);     // [4][4M] us (over nzB, dead)
  float*  z     = (float*)(w8 + 64*MB);      // [2][4M] f32 (over qS, dead)
  // ---- FFN-phase layout ----
  ushort* wf2B  = (ushort*)(w8);             // 32MB (over wqkvB+woB)
  ushort* h1c   = (ushort*)(w8 + 32*MB);     // [4][4M] us (over oBc)
  ushort* wf1B  = (ushort*)(w8 + 96*MB);     // 32MB (over kS)
  ushort* wgB   = (ushort*)(w8 + 128*MB);    // 8MB (over vtS)
  ushort* nz2c  = (ushort*)(w8 + 136*MB);    // [4][1M] us (8MB)
  float*  p0F   = (float*)(w8 + 136*MB);     // f32 [2][1M] partial 0 (alias nz2c)
  ushort* hBc   = (ushort*)(w8 + 144*MB);    // [4][1M] us (8MB)
  float*  p1F   = (float*)(w8 + 152*MB);     // f32 [2][1M] partial 1

  dim3 blk(256), blk5(512);
  // ---- attention branch ----
  cvt_split<<<1024, blk, 0, stream>>>(wq, wqkvB,        M1);
  cvt_split<<<1024, blk, 0, stream>>>(wk, wqkvB + 4*M1, M1);
  cvt_split<<<1024, blk, 0, stream>>>(wv, wqkvB + 8*M1, M1);
  cvt_split<<<1024, blk, 0, stream>>>(wo, woB,          M1);
  cln_kernel<<<dim3(BT_,2), blk, 0, stream>>>(x, (long)PL, 0, g1, b1, nzB, M4);
  // Q,K = nz @ {wq,wk}^T + b  (gz = weight set), full M=4096
  cgemm_split<128,128,64,32,512><<<dim3(8,32,2), blk5, 0, stream>>>(
      nzB, M4, wqkvB, M1, 4*M1, bq, bk, nullptr,
      nullptr, nullptr, nullptr, 0, 0, qS, M4, 4*M4,
      4096, 1024, 1024, 0, 0, 0);
  // V^T = wv @ nz^T + bv(row): [1024 d][4096 t]
  cgemm_split<128,128,64,32,512><<<dim3(32,8,1), blk5, 0, stream>>>(
      wqkvB + 8*M1, M1, nzB, M4, 0, bv, nullptr, nullptr,
      nullptr, nullptr, nullptr, 0, 0, vtS, M4, 0,
      1024, 4096, 1024, 0, 1, 0);
  rope_table<<<256, blk, 0, stream>>>(ropeT);
  rope_split<<<16384, blk, 0, stream>>>(qS, kS, ropeT, M4);
  attn_mfma<<<dim3(64,16), blk, 0, stream>>>(qS, kS, vtS, M4, oBc, M4);
  // z = o @ wo^T + bo + x (residual), full M=4096
  cgemm_split<128,128,64,32,512><<<dim3(8,32,1), blk5, 0, stream>>>(
      oBc, M4, woB, M1, 0, bo, nullptr, nullptr,
      x, x + PL, z, (long)PL, 0, nullptr, 0, 0,
      4096, 1024, 1024, 0, 0, 0);
  // ---- FFN branch ----
  cvt_split<<<4096, blk, 0, stream>>>(wf1, wf1B, M4);
  cvt_split<<<4096, blk, 0, stream>>>(wf2, wf2B, M4);
  cvt_split<<<1024, blk, 0, stream>>>(wg, wgB, M1);
  for (int c=0; c<4; c++){
    cln_kernel<<<dim3(1024,2), blk, 0, stream>>>(z, (long)PL, c*1024, g2, b2, nz2c, M1);
    cgemm_split<128,128,64,32,512><<<dim3(32,8,1), blk5, 0, stream>>>(
        nz2c, M1, wf1B, M4, 0, bf1, nullptr, nullptr,
        nullptr, nullptr, nullptr, 0, 0, h1c, M4, 0,
        1024, 4096, 1024, 1, 0, 0);
    // wf2: split-K=2 over K=4096; f32 partials p0 (bias) / p1
    cgemm_split<128,64,64,32,256><<<dim3(16,8,2), blk, 0, stream>>>(
        h1c, M4, wf2B, M4, 0, bf2, nullptr, nullptr,
        nullptr, nullptr, p0F, M1, M4, nullptr, 0, 0,
        1024, 1024, 4096, 0, 0, 2048);
    hsum_kernel<<<4096, blk, 0, stream>>>(p0F, p1F, hBc);
    // wg: split-K=2 over K=1024; partials p0 (bias bg) / p1
    cgemm_split<128,64,64,32,256><<<dim3(16,8,2), blk, 0, stream>>>(
        hBc, M1, wgB, M1, 0, bg, nullptr, nullptr,
        nullptr, nullptr, p0F, M1, M4, nullptr, 0, 0,
        1024, 1024, 1024, 0, 0, 512);
    gate_kernel<<<4096, blk, 0, stream>>>(z, hBc, p0F, p1F, out, c*(int)M1);
  }
}